// Round 9
// baseline (308.332 us; speedup 1.0000x reference)
//
#include <hip/hip_runtime.h>
#include <stdint.h>
#include <math.h>

#define DEVINL __device__ __forceinline__

constexpr int SEQ = 2048;
constexpr int DIM = 512;
constexpr int BATCH = 2;
constexpr int NROWS = BATCH * SEQ;        // 4096
constexpr int NRAND = (SEQ * SEQ) / 2;    // 2^21
constexpr float F32_TINY = 1.1754943508222875e-38f;

typedef float float4v __attribute__((ext_vector_type(4)));
typedef short short8 __attribute__((ext_vector_type(8)));
typedef unsigned long long u64;

DEVINL float4v MFMA(short8 a, short8 b, float4v c) {
  return __builtin_amdgcn_mfma_f32_16x16x32_bf16(a, b, c, 0, 0, 0);
}

DEVINL ushort f2bf(float x) {
  uint32_t u = __float_as_uint(x);
  return (ushort)((u + 0x7FFFu + ((u >> 16) & 1u)) >> 16);
}

// 16-lane max reduction via DPP row rotations (VALU-rate, no DS pipe)
template <int CTRL>
DEVINL float dpp_max_step(float v) {
  int r = __builtin_amdgcn_update_dpp(0, __float_as_int(v), CTRL, 0xF, 0xF, true);
  return fmaxf(v, __int_as_float(r));
}
DEVINL float rowmax16(float v) {
  v = dpp_max_step<0x121>(v);   // row_ror:1
  v = dpp_max_step<0x122>(v);   // row_ror:2
  v = dpp_max_step<0x124>(v);   // row_ror:4
  v = dpp_max_step<0x128>(v);   // row_ror:8
  return v;
}

// ---------------- threefry2x32 (JAX-compatible) ----------------
__host__ __device__ inline void tf2x32(uint32_t k0, uint32_t k1,
                                       uint32_t x0, uint32_t x1,
                                       uint32_t* o0, uint32_t* o1) {
  uint32_t ks2 = k0 ^ k1 ^ 0x1BD11BDAu;
  x0 += k0; x1 += k1;
#define TFR(r) { x0 += x1; x1 = (x1 << (r)) | (x1 >> (32 - (r))); x1 ^= x0; }
  TFR(13) TFR(15) TFR(26) TFR(6)
  x0 += k1; x1 += ks2 + 1u;
  TFR(17) TFR(29) TFR(16) TFR(24)
  x0 += ks2; x1 += k0 + 2u;
  TFR(13) TFR(15) TFR(26) TFR(6)
  x0 += k0; x1 += k1 + 3u;
  TFR(17) TFR(29) TFR(16) TFR(24)
  x0 += k1; x1 += ks2 + 4u;
  TFR(13) TFR(15) TFR(26) TFR(6)
  x0 += ks2; x1 += k0 + 5u;
#undef TFR
  *o0 = x0; *o1 = x1;
}

DEVINL uint32_t jax_bits32(uint32_t k0, uint32_t k1, uint32_t idx) {
  uint32_t a, b;
  tf2x32(k0, k1, 0u, idx, &a, &b);
  return a ^ b;
}

// ---------------- block reductions ----------------
DEVINL float blockReduceSum(float v) {
  __shared__ float sh[16];
  __syncthreads();
  int lane = threadIdx.x & 63, wid = threadIdx.x >> 6;
  #pragma unroll
  for (int o = 32; o > 0; o >>= 1) v += __shfl_down(v, o);
  if (lane == 0) sh[wid] = v;
  __syncthreads();
  if (threadIdx.x == 0) {
    int nw = ((int)blockDim.x + 63) >> 6;
    float s = 0.f;
    for (int i = 0; i < nw; i++) s += sh[i];
    sh[0] = s;
  }
  __syncthreads();
  return sh[0];
}

DEVINL float blockReduceMin(float v) {
  __shared__ float sh[16];
  __syncthreads();
  int lane = threadIdx.x & 63, wid = threadIdx.x >> 6;
  #pragma unroll
  for (int o = 32; o > 0; o >>= 1) v = fminf(v, __shfl_down(v, o));
  if (lane == 0) sh[wid] = v;
  __syncthreads();
  if (threadIdx.x == 0) {
    int nw = ((int)blockDim.x + 63) >> 6;
    float s = sh[0];
    for (int i = 1; i < nw; i++) s = fminf(s, sh[i]);
    sh[0] = s;
  }
  __syncthreads();
  return sh[0];
}

DEVINL float blockReduceMax(float v) {
  __shared__ float sh[16];
  __syncthreads();
  int lane = threadIdx.x & 63, wid = threadIdx.x >> 6;
  #pragma unroll
  for (int o = 32; o > 0; o >>= 1) v = fmaxf(v, __shfl_down(v, o));
  if (lane == 0) sh[wid] = v;
  __syncthreads();
  if (threadIdx.x == 0) {
    int nw = ((int)blockDim.x + 63) >> 6;
    float s = sh[0];
    for (int i = 1; i < nw; i++) s = fmaxf(s, sh[i]);
    sh[0] = s;
  }
  __syncthreads();
  return sh[0];
}

// A-image layout (GEMM A/W operand): chunk (row>>7, k>>5) of 4096 ushorts
DEVINL void store_img_scalar(ushort* img, int row, int d, float v) {
  size_t idx = ((size_t)((row >> 7) * 16 + (d >> 5))) * 4096
             + ((((row & 127) >> 4) * 4 + ((d >> 3) & 3)) * 16 + (row & 15)) * 8 + (d & 7);
  img[idx] = f2bf(v);
}

// ---------------- ln3: LayerNorm ×3 + bf16 image emit ----------------
__global__ __launch_bounds__(256) void ln3_kernel(
    const float* __restrict__ xq, const float* __restrict__ xk, const float* __restrict__ xv,
    const float* __restrict__ gq, const float* __restrict__ bq2,
    const float* __restrict__ gk, const float* __restrict__ bk2,
    const float* __restrict__ gv, const float* __restrict__ bv2,
    float* __restrict__ oq, ushort* __restrict__ iq, ushort* __restrict__ ik,
    ushort* __restrict__ iv) {
  const float *x, *g, *bb; ushort* img;
  if (blockIdx.y == 0)      { x = xq; g = gq; bb = bq2; img = iq; }
  else if (blockIdx.y == 1) { x = xk; g = gk; bb = bk2; img = ik; }
  else                      { x = xv; g = gv; bb = bv2; img = iv; }
  int row = blockIdx.x;
  const float* xr = x + (size_t)row * DIM;
  int t = threadIdx.x;
  float v0 = xr[t], v1 = xr[t + 256];
  float mu = blockReduceSum(v0 + v1) * (1.0f / 512.0f);
  float d0 = v0 - mu, d1 = v1 - mu;
  float var = blockReduceSum(d0 * d0 + d1 * d1) * (1.0f / 512.0f);
  float inv = 1.0f / sqrtf(var + 1e-5f);
  float r0 = d0 * inv * g[t] + bb[t];
  float r1 = d1 * inv * g[t + 256] + bb[t + 256];
  if (blockIdx.y == 0) {
    oq[(size_t)row * DIM + t] = r0;
    oq[(size_t)row * DIM + t + 256] = r1;
  }
  store_img_scalar(img, row, t, r0);
  store_img_scalar(img, row, t + 256, r1);
}

// ---------------- mask-critical f32 bodies (bit-exact, unchanged math) ----------------
DEVINL void gemm_f32_body(const float* __restrict__ A, const float* __restrict__ W,
                          const float* __restrict__ bias, float* __restrict__ C,
                          int bx, int by) {
  __shared__ float As[16][17];
  __shared__ float Ws[16][68];
  int bm = by * 16, bn = bx * 64;
  int tid = threadIdx.x;
  int tx = tid & 15, ty = tid >> 4;
  int lk = tid & 15, lm = tid >> 4;
  float acc[4] = {0.f, 0.f, 0.f, 0.f};
  for (int kk = 0; kk < DIM; kk += 16) {
    __syncthreads();
    As[lk][lm] = A[(size_t)(bm + lm) * DIM + kk + lk];
    #pragma unroll
    for (int i = 0; i < 4; i++)
      Ws[lk][lm + i * 16] = W[(size_t)(bn + lm + i * 16) * DIM + kk + lk];
    __syncthreads();
    #pragma unroll
    for (int k = 0; k < 16; k++) {
      float a = As[k][ty];
      float4 w4 = *(const float4*)&Ws[k][tx * 4];
      acc[0] += a * w4.x; acc[1] += a * w4.y;
      acc[2] += a * w4.z; acc[3] += a * w4.w;
    }
  }
  int m = bm + ty;
  #pragma unroll
  for (int j = 0; j < 4; j++) {
    int n = bn + tx * 4 + j;
    float v = acc[j] + bias[n];
    v = fmaxf(v, 0.f);
    C[(size_t)m * 128 + n] = v;
  }
}

DEVINL void dmstats_body(const float* __restrict__ qn, float* __restrict__ dm,
                         float* __restrict__ mag, float* __restrict__ ch,
                         float* __restrict__ rowvar, int t, int b) {
  const float* x = qn + ((size_t)b * SEQ + t) * DIM;
  int tid = threadIdx.x;
  float sx = 0, sq = 0, sdm = 0, sch = 0;
  float xs[2];
  #pragma unroll
  for (int i = 0; i < 2; i++) {
    int d = tid + i * 256;
    float xv = x[d]; xs[i] = xv;
    sx += xv; sq += xv * xv;
    float acc = 0.f;
    if (t + 1 < SEQ) { float df = fabsf(x[1 * DIM + d] - xv); acc += 0.4f * (df / 1.0f); sch += df; }
    if (t + 2 < SEQ) { float df = fabsf(x[2 * DIM + d] - xv); acc += 0.3f * (df / 2.0f); }
    if (t + 3 < SEQ) { float df = fabsf(x[3 * DIM + d] - xv); acc += 0.2f * (df / 3.0f); }
    if (t + 5 < SEQ) { float df = fabsf(x[5 * DIM + d] - xv); acc += 0.1f * (df / 5.0f); }
    sdm += acc;
  }
  float mu = blockReduceSum(sx) * (1.0f / 512.0f);
  float sv = 0;
  #pragma unroll
  for (int i = 0; i < 2; i++) { float dd = xs[i] - mu; sv += dd * dd; }
  float totsq = blockReduceSum(sq);
  float totdm = blockReduceSum(sdm);
  float totch = blockReduceSum(sch);
  float totsv = blockReduceSum(sv);
  if (tid == 0) {
    size_t idx = (size_t)b * SEQ + t;
    dm[idx] = totdm / 512.0f;
    mag[idx] = sqrtf(totsq);
    ch[idx] = (t + 1 < SEQ) ? (totch / 512.0f) : 0.f;
    rowvar[idx] = totsv / 511.0f;
  }
}

DEVINL void conv_w_hi(const float* __restrict__ src, ushort* __restrict__ dst, int gid) {
  int row = gid >> 6, c8 = gid & 63;
  const float* p = src + (size_t)row * 512 + c8 * 8;
  float4 v0 = ((const float4*)p)[0];
  float4 v1 = ((const float4*)p)[1];
  float xv[8] = {v0.x, v0.y, v0.z, v0.w, v1.x, v1.y, v1.z, v1.w};
  short8 hv;
  #pragma unroll
  for (int j = 0; j < 8; j++) hv[j] = (short)f2bf(xv[j]);
  int mb = row >> 7, rr = row & 127, kkc = c8 >> 2, qrr = c8 & 3;
  ((short8*)dst)[(mb * 16 + kkc) * 512 + ((rr >> 4) * 4 + qrr) * 16 + (rr & 15)] = hv;
}

// mega1: gemm_f32(512) | dmstats(4096) | weight conv(512) | init(1)
__global__ __launch_bounds__(256) void mega1_kernel(
    const float* qn, const float* Ww1, const float* bw1, float* hidden,
    float* dm, float* mag, float* ch, float* rowvar,
    const float* Wq, const float* Wk, const float* Wv, const float* Wo,
    ushort* Wqh, ushort* Wkh, ushort* Wvh, ushort* Woh,
    uint8_t* colm, int* cnt, int* haskp) {
  int bid = blockIdx.x;
  if (bid < 512) {
    gemm_f32_body(qn, Ww1, bw1, hidden, bid & 1, bid >> 1);
  } else if (bid < 4608) {
    int r = bid - 512;
    dmstats_body(qn, dm, mag, ch, rowvar, r & 2047, r >> 11);
  } else if (bid < 5120) {
    int r = bid - 4608;
    const float* s; ushort* d;
    switch (r >> 7) {
      case 0: s = Wq; d = Wqh; break;
      case 1: s = Wk; d = Wkh; break;
      case 2: s = Wv; d = Wvh; break;
      default: s = Wo; d = Woh; break;
    }
    conv_w_hi(s, d, (r & 127) * 256 + (int)threadIdx.x);
  } else {
    int tid = threadIdx.x;
    for (int i = tid; i < BATCH * SEQ; i += 256) colm[i] = 0;
    if (tid < BATCH) { cnt[tid] = 0; haskp[tid] = 0; }
  }
}

// mega2: win(4096, 256-thr zero-padded — bitwise-identical sum) | batchstats(2)
DEVINL void win_body(const float* __restrict__ hidden, const float* __restrict__ Ww2,
                     const float* __restrict__ bw2, int* __restrict__ win, int row) {
  int t = threadIdx.x;
  float v = (t < 128) ? hidden[(size_t)row * 128 + t] * Ww2[t] : 0.f;
  v = blockReduceSum(v);
  if (t == 0) {
    float y = v + bw2[0];
    float sig = 1.0f / (1.0f + expf(-y));
    float adj = 0.5f + sig;
    int w = (int)rintf(64.0f * adj);
    w = w < 1 ? 1 : (w > 128 ? 128 : w);
    win[row] = w;
  }
}

DEVINL void batchstats_body(const float* __restrict__ dm, const float* __restrict__ mag,
                            const float* __restrict__ ch, const float* __restrict__ rowvar,
                            float* __restrict__ impn, float* __restrict__ thr,
                            float* __restrict__ comp, int b) {
  int tid = threadIdx.x;
  float sdm = 0, srv = 0, lo = INFINITY, hi = -INFINITY;
  for (int t = tid; t < SEQ; t += 256) {
    size_t idx = (size_t)b * SEQ + t;
    sdm += dm[idx];
    srv += rowvar[idx];
    float imp = 0.5f * mag[idx] + 0.5f * ch[idx];
    lo = fminf(lo, imp); hi = fmaxf(hi, imp);
  }
  float meandm = blockReduceSum(sdm) * (1.0f / 2048.0f);
  float compv = blockReduceSum(srv) * (1.0f / 2048.0f);
  lo = blockReduceMin(lo);
  hi = blockReduceMax(hi);
  float sv = 0;
  for (int t = tid; t < SEQ; t += 256) {
    float d2 = dm[(size_t)b * SEQ + t] - meandm;
    sv += d2 * d2;
  }
  float var = blockReduceSum(sv) / 2047.0f;
  for (int t = tid; t < SEQ; t += 256) {
    size_t idx = (size_t)b * SEQ + t;
    float imp = 0.5f * mag[idx] + 0.5f * ch[idx];
    impn[idx] = (imp - lo) / (hi - lo + 1e-6f);
  }
  if (tid == 0) { thr[b] = meandm + 0.5f * sqrtf(var); comp[b] = compv; }
}

__global__ __launch_bounds__(256) void mega2_kernel(
    const float* hidden, const float* Ww2, const float* bw2, int* win,
    const float* dm, const float* mag, const float* ch, const float* rowvar,
    float* impn, float* thr, float* comp) {
  int bid = blockIdx.x;
  if (bid < 4096) win_body(hidden, Ww2, bw2, win, bid);
  else batchstats_body(dm, mag, ch, rowvar, impn, thr, comp, bid - 4096);
}

// mega3 (512 threads): kp(8) | topk(8)
__global__ __launch_bounds__(512) void mega3_kernel(
    const float* __restrict__ dm, const float* __restrict__ thr,
    uint8_t* __restrict__ kp, int* __restrict__ haskp,
    const float* __restrict__ impn, uint8_t* __restrict__ colm,
    uint32_t kg0, uint32_t kg1) {
  int bid = blockIdx.x;
  if (bid < 8) {
    int b = bid >> 2;
    int t = (bid & 3) * 512 + (int)threadIdx.x;
    const float* dmb = dm + (size_t)b * SEQ;
    float v = dmb[t];
    float tb = thr[b];
    float prev = (t > 0) ? dmb[t - 1] : -1.0f;
    float next = (t < SEQ - 1) ? dmb[t + 1] : -1.0f;
    bool k = (v > tb) && (v > prev) && (v > next);
    if (t == 0 || t == SEQ - 1) k = k || (v > tb);
    kp[(size_t)b * SEQ + t] = k ? 1 : 0;
    if (k) haskp[b] = 1;
  } else {
    int rowid = bid - 8;
    int b = rowid >> 2, layer = rowid & 3;
    int j = threadIdx.x;
    float pv = impn[(size_t)b * SEQ + layer * 512 + j];
    float ssum = blockReduceSum(pv);
    uint32_t bits2 = jax_bits32(kg0, kg1, (uint32_t)(rowid * 512 + j));
    float f = __uint_as_float((bits2 >> 9) | 0x3F800000u) - 1.0f;
    float u = fmaxf(F32_TINY, f + F32_TINY);
    float g = -logf(-logf(u));
    float score = logf(pv / (ssum + 1e-6f) + 1e-20f) + g;
    __shared__ float sc[512];
    sc[j] = score;
    __syncthreads();
    for (int pick = 0; pick < 4; pick++) {
      if (j < 64) {
        float bv = -INFINITY; int bi = 0;
        #pragma unroll
        for (int q = 0; q < 8; q++) {
          int idx = j + q * 64;
          float v = sc[idx];
          if (v > bv) { bv = v; bi = idx; }
        }
        #pragma unroll
        for (int o = 1; o < 64; o <<= 1) {
          float ov = __shfl_xor(bv, o);
          int oi = __shfl_xor(bi, o);
          if (ov > bv || (ov == bv && oi < bi)) { bv = ov; bi = oi; }
        }
        if (j == 0) {
          colm[(size_t)b * SEQ + layer * 512 + bi] = 1;
          sc[bi] = -INFINITY;
        }
      }
      __syncthreads();
    }
  }
}

DEVINL bool fbcol(int k) {
  return k == 0 || k == 511 || k == 1023 || k == 1535 || k == 2047;
}

// 16 q-rows per block -> 256 atomics total instead of 4096 (same bits, same count)
DEVINL void maskbuild_body16(const int* __restrict__ win, const uint8_t* __restrict__ kp,
                             const uint8_t* __restrict__ colm, const int* __restrict__ haskp,
                             u64* __restrict__ bits, int* __restrict__ cnt, int qg, int b) {
  int hk = haskp[b];
  const uint8_t* kpb = kp + (size_t)b * SEQ;
  const uint8_t* cob = colm + (size_t)b * SEQ;
  int tid = threadIdx.x, wave = tid >> 6, lane = tid & 63;
  int local = 0;
  for (int qq = 0; qq < 16; qq++) {
    int q = qg * 16 + qq;
    int w = win[(size_t)b * SEQ + q];
    bool rowk = hk ? (kpb[q] != 0) : fbcol(q);
    #pragma unroll
    for (int i = 0; i < 8; i++) {
      int k = i * 256 + tid;
      bool colk = hk ? (kpb[k] != 0) : fbcol(k);
      bool mmv = ((k >= q - w) && (k <= q + w)) || rowk || colk || (cob[k] != 0);
      u64 word = __ballot(mmv);
      if (lane == 0) bits[((size_t)b * 32 + (i * 4 + wave)) * 2048 + q] = word;
      local += mmv ? 1 : 0;
    }
  }
  float tot = blockReduceSum((float)local);
  if (tid == 0) atomicAdd(&cnt[b], (int)tot);
}

// ---------------- 64x128 plain-bf16 MFMA GEMM ----------------
// mode 0: f32 C (+resid); 1: K attn image; 2: V attn image (remapped keys); 3: Q image ×0.125
DEVINL void gemm64_body(const ushort* __restrict__ Ahg, const ushort* __restrict__ Whg,
                        const float* __restrict__ bias, const float* __restrict__ resid,
                        float* __restrict__ C, ushort* __restrict__ oImg,
                        int mode, int bx, int by) {
  __shared__ __align__(16) ushort Ah[2048], Wh[4096];
  int tid = threadIdx.x, wave = tid >> 6, lane = tid & 63;
  int mm = lane & 15, qr = lane >> 4;
  int wm = (wave >> 1) * 32, wn = (wave & 1) * 64;
  int bm = by * 64, bn = bx * 128;
  float4v acc[2][4] = {};
  for (int kk = 0; kk < 16; kk++) {
    __syncthreads();
    {
      const short8* ga = (const short8*)(Ahg + ((size_t)((bm >> 7) * 16 + kk)) * 4096
                                         + ((bm >> 6) & 1) * 2048);
      const short8* gw = (const short8*)(Whg + ((size_t)((bn >> 7) * 16 + kk)) * 4096);
      ((short8*)Ah)[tid] = ga[tid];
      ((short8*)Wh)[tid] = gw[tid];
      ((short8*)Wh)[tid + 256] = gw[tid + 256];
    }
    __syncthreads();
    short8 ah[2], bh[4];
    #pragma unroll
    for (int mt = 0; mt < 2; mt++)
      ah[mt] = ((short8*)Ah)[(((wm >> 4) + mt) * 4 + qr) * 16 + mm];
    #pragma unroll
    for (int nt = 0; nt < 4; nt++)
      bh[nt] = ((short8*)Wh)[(((wn >> 4) + nt) * 4 + qr) * 16 + mm];
    #pragma unroll
    for (int mt = 0; mt < 2; mt++)
      #pragma unroll
      for (int nt = 0; nt < 4; nt++)
        acc[mt][nt] = MFMA(ah[mt], bh[nt], acc[mt][nt]);
  }
  #pragma unroll
  for (int mt = 0; mt < 2; mt++)
    #pragma unroll
    for (int nt = 0; nt < 4; nt++) {
      int n = bn + wn + nt * 16 + mm;
      float bsv = bias[n];
      #pragma unroll
      for (int reg = 0; reg < 4; reg++) {
        int m = bm + wm + mt * 16 + qr * 4 + reg;
        float v = acc[mt][nt][reg] + bsv;
        if (mode == 0) {
          if (resid) v += resid[(size_t)m * 512 + n];
          C[(size_t)m * 512 + n] = v;
        } else if (mode == 1) {
          int b2 = m >> 11, sq = m & 2047, t = sq >> 6, r = sq & 63;
          int h2 = n >> 6, d = n & 63;
          size_t pos = ((size_t)((b2 * 8 + h2) * 32 + t)) * 4096
                     + ((((r >> 4) * 2 + (d >> 5)) * 4 + ((d >> 3) & 3)) * 16 + (r & 15)) * 8
                     + (d & 7);
          oImg[pos] = f2bf(v);
        } else if (mode == 2) {
          int b2 = m >> 11, sq = m & 2047, t = sq >> 6, kk2 = sq & 63;
          int h2 = n >> 6, d = n & 63;
          int pk = (kk2 & 15) * 4 + (kk2 >> 4);
          int kc2 = pk >> 5, qf = (pk >> 3) & 3, j = pk & 7, dt = d >> 4;
          size_t pos = ((size_t)((b2 * 8 + h2) * 32 + t)) * 4096
                     + (((kc2 * 4 + dt) * 4 + qf) * 16 + (d & 15)) * 8 + j;
          oImg[pos] = f2bf(v);
        } else {
          int b2 = m >> 11, q = m & 2047, qt = q >> 5, mt2 = (q >> 4) & 1, mmr = q & 15;
          int h2 = n >> 6, d = n & 63, dc = d >> 5, qr2 = (d >> 3) & 3, j = d & 7;
          size_t pos = ((size_t)((b2 * 8 + h2) * 64 + qt)) * 2048
                     + (((mt2 * 2 + dc) * 4 + qr2) * 16 + mmr) * 8 + j;
          oImg[pos] = f2bf(v * 0.125f);
        }
      }
    }
}

// mega4: QKV projections (768) | maskbuild (256, 16 rows each)
__global__ __launch_bounds__(256) void mega4_kernel(
    const ushort* qnh, const ushort* Wqh, const float* bq, ushort* Qimg,
    const ushort* knh, const ushort* Wkh, const float* bk, ushort* Kth,
    const ushort* vnh, const ushort* Wvh, const float* bv, ushort* Vt,
    const int* win, const uint8_t* kp, const uint8_t* colm, const int* haskp,
    u64* bits, int* cnt) {
  int bid = blockIdx.x;
  if (bid < 768) {
    int op = bid >> 8, r = bid & 255;
    int bx = r & 3, by = r >> 2;
    if (op == 0)      gemm64_body(qnh, Wqh, bq, nullptr, nullptr, Qimg, 3, bx, by);
    else if (op == 1) gemm64_body(knh, Wkh, bk, nullptr, nullptr, Kth, 1, bx, by);
    else              gemm64_body(vnh, Wvh, bv, nullptr, nullptr, Vt, 2, bx, by);
  } else {
    int r = bid - 768;          // 0..255 = b*128 + qg
    maskbuild_body16(win, kp, colm, haskp, bits, cnt, r & 127, r >> 7);
  }
}

// fill (needed computed inline, bit-identical float ops)
__global__ void fill_kernel(u64* __restrict__ bits, const float* __restrict__ comp,
                            const int* __restrict__ cnt,
                            uint32_t kq0, uint32_t kq1, uint32_t kk0, uint32_t kk1) {
  int gid = blockIdx.x * blockDim.x + threadIdx.x;
  int b = gid >> 21;
  int r = gid & (NRAND - 1);
  if (b >= BATCH) return;
  float c0 = comp[0], c1 = comp[1];
  float cmin = fminf(c0, c1), cmax = fmaxf(c0, c1);
  float compb = b ? c1 : c0;
  float nc = (compb - cmin) / (cmax - cmin + 1e-6f);
  float ratio = fminf(fmaxf(0.3f * (0.5f + nc), 0.1f), 0.5f);
  float dens = (float)cnt[b] / 4194304.0f;
  float nd = ceilf((ratio - dens) * 4194304.0f);
  int needed = (int)nd;
  if (needed < 0) needed = 0;
  if (r >= needed) return;
  uint32_t flat = 4194304u + (uint32_t)gid;
  uint32_t q = jax_bits32(kq0, kq1, flat) & 2047u;
  uint32_t k = jax_bits32(kk0, kk1, flat) & 2047u;
  atomicOr(&bits[((size_t)b * 32 + (k >> 6)) * 2048 + q], 1ull << (k & 63));
}

// per-lane u32 mask image: tl[((b*64+qt)*32+kc)*64 + lane], bit w=(mt*4+reg)*4+ct
// = sparse(row = qt*32+mt*16+(lane>>4)*4+reg, key = kc*64+ct*16+(lane&15))
__global__ __launch_bounds__(256) void tl_kernel(const u64* __restrict__ bits,
                                                 uint32_t* __restrict__ tl) {
  int bid = blockIdx.x;            // 0..127 = b*64+qt
  int b = bid >> 6, qt = bid & 63;
  int tid = threadIdx.x;
  __shared__ u64 W[32][32];        // [kc][row-local]
  #pragma unroll
  for (int i = 0; i < 4; i++) {
    int idx = i * 256 + tid;
    int kc = idx >> 5, r = idx & 31;
    W[kc][r] = bits[((size_t)(b * 32 + kc)) * 2048 + qt * 32 + r];
  }
  __syncthreads();
  #pragma unroll
  for (int oi = 0; oi < 8; oi++) {
    int o = oi * 256 + tid;
    int kc = o >> 6, lane = o & 63;
    int qr = lane >> 4, mm = lane & 15;
    uint32_t acc = 0;
    #pragma unroll
    for (int mt = 0; mt < 2; mt++)
      #pragma unroll
      for (int reg = 0; reg < 4; reg++) {
        u64 wv = W[kc][mt * 16 + qr * 4 + reg];
        uint32_t lo = (uint32_t)wv, hi = (uint32_t)(wv >> 32);
        int base = (mt * 4 + reg) * 4;
        acc |= ((lo >> mm) & 1u) << base;
        acc |= ((lo >> (16 + mm)) & 1u) << (base + 1);
        acc |= ((hi >> mm) & 1u) << (base + 2);
        acc |= ((hi >> (16 + mm)) & 1u) << (base + 3);
      }
    tl[((size_t)(b * 64 + qt) * 32 + kc) * 64 + lane] = acc;
  }
}

// ---------------- barrier-free MFMA flash attention (v6) ----------------
// XCD swizzle; online-max softmax; DPP row-rotation max (no DS shuffles);
// all 8 mask words preloaded; full unroll for compiler software-pipelining.
__global__ __launch_bounds__(256, 4) void attn_mfma(
    const ushort* __restrict__ Qimg, const ushort* __restrict__ Khig,
    const ushort* __restrict__ Vimg, const uint32_t* __restrict__ tl,
    ushort* __restrict__ Oimg) {
  int L = blockIdx.x;
  int xcd = L & 7, j = L >> 3;
  int bh = xcd * 2 + (j >> 6);
  int qt = j & 63;
  int b = bh >> 3, h = bh & 7;
  __shared__ __align__(16) char arena[34 * 1024];
  float* LO = (float*)arena;                       // [4*32][64] merge
  float* Lm = (float*)(arena + 32768);             // [4*32]
  float* Ll = (float*)(arena + 32768 + 512);       // [4*32]
  int tid = threadIdx.x;
  int wave = __builtin_amdgcn_readfirstlane(tid >> 6);
  int lane = tid & 63;
  int mm = lane & 15, qr = lane >> 4;
  int q0 = qt * 32;
  ushort* pw = (ushort*)arena + wave * 2048;       // wave-private P (4 KB)

  short8 aq[2][2];
  {
    const short8* qp = (const short8*)(Qimg + ((size_t)((b * 8 + h) * 64 + qt)) * 2048);
    #pragma unroll
    for (int mt = 0; mt < 2; mt++)
      #pragma unroll
      for (int dc = 0; dc < 2; dc++)
        aq[mt][dc] = qp[((mt * 2 + dc) * 4 + qr) * 16 + mm];
  }
  // preload all 8 iteration mask words (independent VMEM, 8 VGPR)
  const uint32_t* tlb = tl + ((size_t)(b * 64 + qt)) * 32 * 64 + lane;
  uint32_t mwAll[8];
  #pragma unroll
  for (int it = 0; it < 8; it++) mwAll[it] = tlb[(size_t)(it * 4 + wave) * 64];

  float4v accO[2][4] = {};
  float4v accL2[2] = {};
  float m_i[2][4];
  #pragma unroll
  for (int mt = 0; mt < 2; mt++)
    #pragma unroll
    for (int r = 0; r < 4; r++) m_i[mt][r] = -INFINITY;
  size_t kvbase = ((size_t)((b * 8 + h) * 32)) * 4096;
  const short8 ones8 = {16256, 16256, 16256, 16256, 16256, 16256, 16256, 16256};

  #pragma unroll
  for (int it = 0; it < 8; it++) {
    int kc = it * 4 + wave;
    const short8* kh = (const short8*)(Khig + kvbase + (size_t)kc * 4096);
    const short8* vv = (const short8*)(Vimg + kvbase + (size_t)kc * 4096);
    uint32_t mw = mwAll[it];
    // V fragments issued early (consumed only after softmax)
    short8 vf[2][4];
    #pragma unroll
    for (int kc2 = 0; kc2 < 2; kc2++)
      #pragma unroll
      for (int dt = 0; dt < 4; dt++)
        vf[kc2][dt] = vv[((kc2 * 4 + dt) * 4 + qr) * 16 + mm];
    // QK^T, single bf16 (scale pre-folded into Q image)
    float4v S[2][4];
    #pragma unroll
    for (int ct = 0; ct < 4; ct++) {
      short8 k0 = kh[((ct * 2 + 0) * 4 + qr) * 16 + mm];
      short8 k1 = kh[((ct * 2 + 1) * 4 + qr) * 16 + mm];
      #pragma unroll
      for (int mt = 0; mt < 2; mt++) {
        float4v s = {};
        s = MFMA(aq[mt][0], k0, s);
        s = MFMA(aq[mt][1], k1, s);
        S[mt][ct] = s;
      }
    }
    // online-max masked softmax (DPP max); P packed to wave-private LDS
    #pragma unroll
    for (int mt = 0; mt < 2; mt++) {
      #pragma unroll
      for (int reg = 0; reg < 4; reg++) {
        int base = (mt * 4 + reg) * 4;
        float s[4];
        #pragma unroll
        for (int ct = 0; ct < 4; ct++) {
          float bitf = (float)((mw >> (base + ct)) & 1u);
          s[ct] = fmaf(bitf, -1e30f, S[mt][ct][reg]);
        }
        float mx = fmaxf(fmaxf(s[0], s[1]), fmaxf(s[2], s[3]));
        mx = rowmax16(mx);
        float mn = fmaxf(m_i[mt][reg], mx);
        float alpha = __expf(m_i[mt][reg] - mn);
        m_i[mt][reg] = mn;
        float p[4];
        #pragma unroll
        for (int ct = 0; ct < 4; ct++) p[ct] = __expf(s[ct] - mn);
        #pragma unroll
        for (int dt = 0; dt < 4; dt++) accO[mt][dt][reg] *= alpha;
        accL2[mt][reg] *= alpha;
        uint32_t lo32 = __builtin_amdgcn_perm(__float_as_uint(p[1]), __float_as_uint(p[0]), 0x07060302u);
        uint32_t hi32 = __builtin_amdgcn_perm(__float_as_uint(p[3]), __float_as_uint(p[2]), 0x07060302u);
        int r = qr * 4 + reg;
        int cp = (mm >> 1) ^ (r & 7);
        *(u64*)(pw + mt * 1024 + r * 64 + cp * 8 + (mm & 1) * 4) = ((u64)hi32 << 32) | lo32;
      }
    }
    // PV + ones-column (row-sum l for free)
    #pragma unroll
    for (int mt = 0; mt < 2; mt++)
      #pragma unroll
      for (int kc2 = 0; kc2 < 2; kc2++) {
        int cp = (kc2 * 4 + qr) ^ (mm & 7);
        short8 ap = *(const short8*)(pw + mt * 1024 + mm * 64 + cp * 8);
        #pragma unroll
        for (int dt = 0; dt < 4; dt++)
          accO[mt][dt] = MFMA(ap, vf[kc2][dt], accO[mt][dt]);
        accL2[mt] = MFMA(ap, ones8, accL2[mt]);
      }
  }
  // exact flash merge across the 4 waves
  __syncthreads();
  #pragma unroll
  for (int mt = 0; mt < 2; mt++)
    #pragma unroll
    for (int reg = 0; reg < 4; reg++) {
      int r = mt * 16 + qr * 4 + reg;
      if (mm == 0) {
        Lm[wave * 32 + r] = m_i[mt][reg];
        Ll[wave * 32 + r] = accL2[mt][reg];
      }
      #pragma unroll
      for (int dt = 0; dt < 4; dt++)
        LO[(size_t)(wave * 32 + r) * 64 + dt * 16 + mm] = accO[mt][dt][reg];
    }
  __syncthreads();
  int row = tid >> 3, c0 = (tid & 7) * 8;
  float M = Lm[row];
  #pragma unroll
  for (int w = 1; w < 4; w++) M = fmaxf(M, Lm[w * 32 + row]);
  float fw[4], l = 0.f;
  #pragma unroll
  for (int w = 0; w < 4; w++) {
    fw[w] = __expf(Lm[w * 32 + row] - M);
    l += fw[w] * Ll[w * 32 + row];
  }
  float o[8] = {};
  #pragma unroll
  for (int w = 0; w < 4; w++) {
    const float* lob = LO + (size_t)(w * 32 + row) * 64 + c0;
    #pragma unroll
    for (int c = 0; c < 8; c++) o[c] += fw[w] * lob[c];
  }
  float invl = 1.0f / l;
  short8 o8;
  #pragma unroll
  for (int c = 0; c < 8; c++) o8[c] = (short)f2bf(o[c] * invl);
  int rowg = b * SEQ + q0 + row;
  int col = h * 64 + c0;
  int mb = rowg >> 7, rr = rowg & 127, kkc = col >> 5, qrk = (col >> 3) & 3;
  *(short8*)(Oimg + ((size_t)(mb * 16 + kkc)) * 4096
             + (((rr >> 4) * 4 + qrk) * 16 + (rr & 15)) * 8) = o8;
}

__global__ __launch_bounds__(256) void oproj_kernel(
    const ushort* __restrict__ Oimg, const ushort* __restrict__ Woh,
    const float* __restrict__ bo, const float* __restrict__ resid,
    float* __restrict__ out) {
  gemm64_body(Oimg, Woh, bo, resid, out, nullptr, 0, blockIdx.x, blockIdx.y);
}

// ---------------- launcher ----------------
extern "C" void kernel_launch(void* const* d_in, const int* in_sizes, int n_in,
                              void* d_out, int out_size, void* d_ws, size_t ws_size,
                              hipStream_t stream) {
  (void)in_sizes; (void)n_in; (void)out_size; (void)ws_size;
  const float* queries = (const float*)d_in[0];
  const float* keys    = (const float*)d_in[1];
  const float* values  = (const float*)d_in[2];
  const float* ln_q_g  = (const float*)d_in[3];
  const float* ln_q_b  = (const float*)d_in[4];
  const float* ln_k_g  = (const float*)d_in[5];
  const float* ln_k_b  = (const float*)d_in[6];
  const float* ln_v_g  = (const float*)d_in[7];
  const float* ln_v_b  = (const float*)d_in[8];
  const float* Wq = (const float*)d_in[9];  const float* bq = (const float*)d_in[10];
  const float* Wk = (const float*)d_in[11]; const float* bk = (const float*)d_in[12];
  const float* Wv = (const float*)d_in[13]; const float* bv = (const float*)d_in[14];
  const float* Wo = (const float*)d_in[15]; const float* bo = (const float*)d_in[16];
  const float* Ww1 = (const float*)d_in[17]; const float* bw1 = (const float*)d_in[18];
  const float* Ww2 = (const float*)d_in[19]; const float* bw2 = (const float*)d_in[20];

  char* ws = (char*)d_ws;
  const size_t MB = 1u << 20;
  float*  qn   = (float*)(ws + 0 * MB);          // 8 MB (front 4 MB reused as Oimg)
  ushort* qnh  = (ushort*)(ws + 8 * MB);         // 4 MB
  ushort* knh  = (ushort*)(ws + 12 * MB);        // 4 MB
  ushort* vnh  = (ushort*)(ws + 16 * MB);        // 4 MB
  ushort* Qimg = (ushort*)(ws + 20 * MB);        // 4 MB
  ushort* Kth  = (ushort*)(ws + 24 * MB);        // 4 MB
  ushort* Vt   = (ushort*)(ws + 28 * MB);        // 4 MB
  ushort* Wqh  = (ushort*)(ws + 32 * MB);        // 0.5 MB each
  ushort* Wkh  = (ushort*)(ws + 32 * MB + 524288);
  ushort* Wvh  = (ushort*)(ws + 33 * MB);
  ushort* Woh  = (ushort*)(ws + 33 * MB + 524288);
  u64*    bits = (u64*)(ws + 34 * MB);           // 1 MB
  uint32_t* tl = (uint32_t*)(ws + 35 * MB);      // 1 MB
  float*  hidden = (float*)(ws + 36 * MB);       // 2 MB
  char* st = ws + 38 * MB;
  float* dm     = (float*)st; st += NROWS * 4;
  float* mag    = (float*)st; st += NROWS * 4;
  float* ch     = (float*)st; st += NROWS * 4;
  float* rowvar = (float*)st; st += NROWS * 4;
  float* impn   = (float*)st; st += NROWS * 4;
  int*   win    = (int*)st;   st += NROWS * 4;
  uint8_t* kp   = (uint8_t*)st; st += NROWS;
  uint8_t* colm = (uint8_t*)st; st += NROWS;
  float* thr    = (float*)st; st += 2 * 4;
  float* comp   = (float*)st; st += 2 * 4;
  int* cnt      = (int*)st;   st += 2 * 4;
  int* haskp    = (int*)st;   st += 2 * 4;
  ushort* Oimg = (ushort*)qn;   // qn dead after mega1/mega2

  uint32_t kg0, kg1, kq0, kq1, kk0, kk1;
  tf2x32(0u, 42u, 0u, 0u, &kg0, &kg1);
  tf2x32(0u, 42u, 0u, 1u, &kq0, &kq1);
  tf2x32(0u, 42u, 0u, 2u, &kk0, &kk1);

  dim3 gln(NROWS, 3);
  ln3_kernel<<<gln, 256, 0, stream>>>(queries, keys, values,
                                      ln_q_g, ln_q_b, ln_k_g, ln_k_b, ln_v_g, ln_v_b,
                                      qn, qnh, knh, vnh);

  mega1_kernel<<<5121, 256, 0, stream>>>(qn, Ww1, bw1, hidden, dm, mag, ch, rowvar,
                                         Wq, Wk, Wv, Wo, Wqh, Wkh, Wvh, Woh,
                                         colm, cnt, haskp);

  mega2_kernel<<<4098, 256, 0, stream>>>(hidden, Ww2, bw2, win,
                                         dm, mag, ch, rowvar, impn, thr, comp);

  mega3_kernel<<<16, 512, 0, stream>>>(dm, thr, kp, haskp, impn, colm, kg0, kg1);

  mega4_kernel<<<768 + 256, 256, 0, stream>>>(qnh, Wqh, bq, Qimg,
                                              knh, Wkh, bk, Kth,
                                              vnh, Wvh, bv, Vt,
                                              win, kp, colm, haskp, bits, cnt);

  fill_kernel<<<(2 * NRAND) / 256, 256, 0, stream>>>(bits, comp, cnt, kq0, kq1, kk0, kk1);

  tl_kernel<<<128, 256, 0, stream>>>(bits, tl);

  attn_mfma<<<1024, 256, 0, stream>>>(Qimg, Kth, Vt, tl, Oimg);

  dim3 go(4, 64);
  oproj_kernel<<<go, 256, 0, stream>>>(Oimg, Woh, bo, queries, (float*)d_out);
}